// Round 7
// baseline (255.100 us; speedup 1.0000x reference)
//
#include <hip/hip_runtime.h>

typedef unsigned short u16;
typedef unsigned int   u32;
using bf16x8 = __attribute__((ext_vector_type(8))) short;
using f32x4  = __attribute__((ext_vector_type(4))) float;
using u32x4  = __attribute__((ext_vector_type(4))) u32;

static constexpr int Bb = 8, Ll = 1024, Cc = 1024, Hh = 16, Dd = 64;
static constexpr int Mrows = Bb * Ll;   // 8192
static constexpr int N3    = 3 * Cc;    // 3072
// exp(S/8) = 2^(S * 0.125*log2(e)); fold into q at the QKV epilogue
static constexpr float QSCALE = 0.125f * 1.44269504088896f;

__device__ __forceinline__ u16 f2b(float f) {  // fp32 -> bf16 RNE
    u32 u = __builtin_bit_cast(u32, f);
    u += 0x7FFFu + ((u >> 16) & 1u);
    return (u16)(u >> 16);
}
__device__ __forceinline__ float b2f(u16 u) {
    return __builtin_bit_cast(float, (u32)u << 16);
}
__device__ __forceinline__ u32 pack2bf(float a, float b) {
    return (u32)f2b(a) | ((u32)f2b(b) << 16);
}
// async global->LDS, 16B/lane; LDS dest is wave-uniform base (lane*16 HW-added)
__device__ __forceinline__ void gload16(const u16* g, u16* l) {
    __builtin_amdgcn_global_load_lds(
        (const __attribute__((address_space(1))) void*)g,
        (__attribute__((address_space(3))) void*)l, 16, 0, 0);
}

// ---------------- fp32 -> bf16 convert, 16 elems/thread ----------------
__global__ void k_f32_to_bf16(const float* __restrict__ in, u16* __restrict__ out, int n16) {
    int idx = blockIdx.x * blockDim.x + threadIdx.x;
    if (idx >= n16) return;
    #pragma unroll
    for (int h = 0; h < 2; ++h) {
        f32x4 v0 = *((const f32x4*)in + idx * 4 + h * 2);
        f32x4 v1 = *((const f32x4*)in + idx * 4 + h * 2 + 1);
        u32x4 o;
        o[0] = pack2bf(v0[0], v0[1]);
        o[1] = pack2bf(v0[2], v0[3]);
        o[2] = pack2bf(v1[0], v1[1]);
        o[3] = pack2bf(v1[2], v1[3]);
        *((u32x4*)out + idx * 2 + h) = o;
    }
}

// ---- fused weight transpose+convert: W_qkv (1024x3072) and W_proj (1024x1024) ----
__global__ void k_transpose_w(const float* __restrict__ Wqkv, u16* __restrict__ WqkvT,
                              const float* __restrict__ Wproj, u16* __restrict__ WprojT) {
    __shared__ float tile[32][33];
    int bx = blockIdx.x;
    const float* in; u16* out; int Cn;
    if (bx < 96) { in = Wqkv;  out = WqkvT;  Cn = N3; }
    else         { in = Wproj; out = WprojT; Cn = Cc; bx -= 96; }
    const int R = Cc;   // 1024 rows for both
    int tx = threadIdx.x, ty = threadIdx.y;
    int c = bx * 32 + tx;
    int rbase = blockIdx.y * 32;
    #pragma unroll
    for (int rr = 0; rr < 4; ++rr)
        tile[ty + rr * 8][tx] = in[(size_t)(rbase + ty + rr * 8) * Cn + c];
    __syncthreads();
    int ro = bx * 32 + ty;
    #pragma unroll
    for (int rr = 0; rr < 4; ++rr)
        out[(size_t)(ro + rr * 8) * R + rbase + tx] = f2b(tile[tx][ty + rr * 8]);
}

// ---------------- 128x128 bf16 MFMA GEMM for QKV (reg-staged, stride-40 LDS) ----------------
// K-loop is the proven R2/R6 structure -- DO NOT PERTURB. Epilogue scatters q,k
// to (B,H,L,D) and v directly TRANSPOSED to (B,H,D,L) (vt), killing the separate
// transpose kernel.
__global__ __launch_bounds__(256)
void k_gemm_qkv(const u16* __restrict__ A, const u16* __restrict__ Bt,
                const float* __restrict__ bias,
                u16* __restrict__ qo, u16* __restrict__ ko, u16* __restrict__ vto)
{
    const int M = Mrows, N = N3, K = Cc;
    __shared__ u16 As[128 * 40];
    __shared__ u16 Bs[128 * 40];
    const int tid = threadIdx.x;
    const int wid = tid >> 6, lane = tid & 63;
    const int lr = lane & 15, lg = lane >> 4;
    const int wr = wid >> 1, wc = wid & 1;
    const int nwg = gridDim.x * gridDim.y;
    const int flat = blockIdx.y * gridDim.x + blockIdx.x;
    const int swz = (flat & 7) * (nwg >> 3) + (flat >> 3);
    const int bx = swz % gridDim.x, by = swz / gridDim.x;
    const int row0 = by * 128, col0 = bx * 128;

    const int sRow = tid >> 2;          // 0..63
    const int sK   = (tid & 3) << 3;    // 0,8,16,24
    const u16* aP = A  + (size_t)(row0 + sRow) * K + sK;
    const u16* bP = Bt + (size_t)(col0 + sRow) * K + sK;
    const size_t half = (size_t)64 * K;

    f32x4 acc[4][4] = {};

    u32x4 ra0 = *(const u32x4*)aP;
    u32x4 ra1 = *(const u32x4*)(aP + half);
    u32x4 rb0 = *(const u32x4*)bP;
    u32x4 rb1 = *(const u32x4*)(bP + half);

    for (int k0 = 0; k0 < K; k0 += 32) {
        __syncthreads();
        *(u32x4*)&As[sRow * 40 + sK]        = ra0;
        *(u32x4*)&As[(64 + sRow) * 40 + sK] = ra1;
        *(u32x4*)&Bs[sRow * 40 + sK]        = rb0;
        *(u32x4*)&Bs[(64 + sRow) * 40 + sK] = rb1;
        __syncthreads();
        if (k0 + 32 < K) {               // prefetch next K-tile (overlaps MFMA)
            ra0 = *(const u32x4*)(aP + k0 + 32);
            ra1 = *(const u32x4*)(aP + half + k0 + 32);
            rb0 = *(const u32x4*)(bP + k0 + 32);
            rb1 = *(const u32x4*)(bP + half + k0 + 32);
        }
        bf16x8 af[4], bfv[4];
        #pragma unroll
        for (int m = 0; m < 4; ++m)
            af[m] = *(const bf16x8*)&As[(wr * 64 + m * 16 + lr) * 40 + lg * 8];
        #pragma unroll
        for (int n = 0; n < 4; ++n)
            bfv[n] = *(const bf16x8*)&Bs[(wc * 64 + n * 16 + lr) * 40 + lg * 8];
        #pragma unroll
        for (int m = 0; m < 4; ++m)
            #pragma unroll
            for (int n = 0; n < 4; ++n)
                acc[m][n] = __builtin_amdgcn_mfma_f32_16x16x32_bf16(af[m], bfv[n], acc[m][n], 0, 0, 0);
    }

    #pragma unroll
    for (int m = 0; m < 4; ++m) {
        int rb2 = row0 + wr * 64 + m * 16 + lg * 4;
        #pragma unroll
        for (int n = 0; n < 4; ++n) {
            int cg = col0 + wc * 64 + n * 16 + lr;
            float bv = bias[cg];
            int which = cg >> 10;         // 0=q 1=k 2=v
            float sc = (which == 0) ? QSCALE : 1.0f;   // fold attn scale into q
            int cc2 = cg & 1023;
            int h = cc2 >> 6, dd = cc2 & 63;
            #pragma unroll
            for (int r = 0; r < 4; ++r) {
                int rg = rb2 + r;
                int bidx = rg >> 10, ll2 = rg & 1023;
                u16 val = f2b((acc[m][n][r] + bv) * sc);
                if (which == 0)
                    qo[((size_t)(bidx * Hh + h) * Ll + ll2) * Dd + dd] = val;
                else if (which == 1)
                    ko[((size_t)(bidx * Hh + h) * Ll + ll2) * Dd + dd] = val;
                else  // v: write transposed (bh, D, L); r-consecutive = contiguous
                    vto[((size_t)(bidx * Hh + h) * Dd + dd) * Ll + ll2] = val;
            }
        }
    }
}

// ---- proj GEMM: T3-minimum 2-phase dbuf + global_load_lds + source-side XOR swizzle ----
// EXPERIMENT (contained): double-buffered LDS, stage(t+1) issued BEFORE compute(t),
// ONE barrier per K-step. Linear LDS dest (gload_lds requirement); bank conflicts
// fixed by swizzling the SOURCE 16B-chunk (col16 ^= row&3) and reading with the
// same XOR -> 2-way (free). Unrolled x2 so buffer index is compile-time.
__global__ __launch_bounds__(256)
void k_gemm_proj(const u16* __restrict__ A, const u16* __restrict__ Bt,
                 const float* __restrict__ bias, float* __restrict__ outf)
{
    const int N = Cc, K = Cc;
    __shared__ u16 As[2][128 * 32];
    __shared__ u16 Bs[2][128 * 32];
    const int tid = threadIdx.x;
    const int wid = tid >> 6, lane = tid & 63;
    const int lr = lane & 15, lg = lane >> 4;
    const int wr = wid >> 1, wc = wid & 1;
    const int nwg = gridDim.x * gridDim.y;
    const int flat = blockIdx.y * gridDim.x + blockIdx.x;
    const int swz = (flat & 7) * (nwg >> 3) + (flat >> 3);
    const int bx = swz % gridDim.x, by = swz / gridDim.x;
    const int row0 = by * 128, col0 = bx * 128;

    // staging: lane covers row = wid*32 + (lane>>2) (+16 on 2nd inst),
    // 16B-chunk = (lane&3) ^ (row&3)  [source-side swizzle]
    const int srow = wid * 32 + (lane >> 2);
    const int schk = (lane & 3) ^ (srow & 3);
    const u16* aP = A  + (size_t)(row0 + srow) * K + schk * 8;
    const u16* bP = Bt + (size_t)(col0 + srow) * K + schk * 8;
    const size_t r16 = (size_t)16 * K;
    u16* aL0 = &As[0][wid * 32 * 32]; u16* aL0b = aL0 + 16 * 32;
    u16* bL0 = &Bs[0][wid * 32 * 32]; u16* bL0b = bL0 + 16 * 32;
    u16* aL1 = &As[1][wid * 32 * 32]; u16* aL1b = aL1 + 16 * 32;
    u16* bL1 = &Bs[1][wid * 32 * 32]; u16* bL1b = bL1 + 16 * 32;

    f32x4 acc[4][4] = {};

#define STAGE0(kk) { gload16(aP + (kk), aL0); gload16(aP + r16 + (kk), aL0b); \
                     gload16(bP + (kk), bL0); gload16(bP + r16 + (kk), bL0b); }
#define STAGE1(kk) { gload16(aP + (kk), aL1); gload16(aP + r16 + (kk), aL1b); \
                     gload16(bP + (kk), bL1); gload16(bP + r16 + (kk), bL1b); }
#define COMPUTE(bufi) { \
        bf16x8 af[4], bfv[4]; \
        _Pragma("unroll") \
        for (int m = 0; m < 4; ++m) { int rw = wr * 64 + m * 16 + lr; \
            af[m] = *(const bf16x8*)&As[bufi][rw * 32 + ((lg ^ (rw & 3)) * 8)]; } \
        _Pragma("unroll") \
        for (int n = 0; n < 4; ++n) { int rw = wc * 64 + n * 16 + lr; \
            bfv[n] = *(const bf16x8*)&Bs[bufi][rw * 32 + ((lg ^ (rw & 3)) * 8)]; } \
        _Pragma("unroll") \
        for (int m = 0; m < 4; ++m) \
            _Pragma("unroll") \
            for (int n = 0; n < 4; ++n) \
                acc[m][n] = __builtin_amdgcn_mfma_f32_16x16x32_bf16(af[m], bfv[n], acc[m][n], 0, 0, 0); }

    STAGE0(0);
    __syncthreads();                       // buf0 ready
    for (int k0 = 0; k0 < K; k0 += 64) {
        if (k0 + 32 < K) STAGE1(k0 + 32);  // issue BEFORE compute: latency hides
        COMPUTE(0);
        __syncthreads();                   // drains vmcnt: buf1 ready, buf0 reads done
        if (k0 + 64 < K) STAGE0(k0 + 64);
        COMPUTE(1);
        __syncthreads();
    }
#undef STAGE0
#undef STAGE1
#undef COMPUTE

    #pragma unroll
    for (int m = 0; m < 4; ++m) {
        int rb2 = row0 + wr * 64 + m * 16 + lg * 4;
        #pragma unroll
        for (int n = 0; n < 4; ++n) {
            int cg = col0 + wc * 64 + n * 16 + lr;
            float bv = bias[cg];
            #pragma unroll
            for (int r = 0; r < 4; ++r)
                outf[(size_t)(rb2 + r) * N + cg] = acc[m][n][r] + bv;
        }
    }
}

// ---------------- attention pass 1: column sums ----------------
// Z_j = sum_{i>=j} 2^(S'[i,j]). Wave owns 32 cols; diagonal peeled; mask-free
// main loop. 512 blocks: 8 XCD x 16 bh x 4 tile-pairs.  [frozen since R4]
__global__ __launch_bounds__(256)
void k_attn_colsum(const u16* __restrict__ Q, const u16* __restrict__ Kb,
                   float* __restrict__ zinv)
{
    const int tid = threadIdx.x;
    const int wid = tid >> 6, lane = tid & 63;
    const int lr = lane & 15, lg = lane >> 4;
    const int fid = blockIdx.x;
    const int xcd = fid & 7, n = fid >> 3;
    const int pr = n & 3;
    const int bh = (xcd << 4) | (n >> 2);
    const u16* Qp = Q  + (size_t)bh * Ll * Dd;
    const u16* Kp = Kb + (size_t)bh * Ll * Dd;
    const bool dmask[4] = { lg * 4 + 0 >= lr, lg * 4 + 1 >= lr,
                            lg * 4 + 2 >= lr, lg * 4 + 3 >= lr };

    #pragma unroll
    for (int t = 0; t < 2; ++t) {
        const int xt = t ? (7 - pr) : pr;
        const int jw = xt * 128 + wid * 32;
        bf16x8 kb[2][2];
        #pragma unroll
        for (int g = 0; g < 2; ++g) {
            kb[g][0] = *(const bf16x8*)&Kp[(jw + g * 16 + lr) * Dd + lg * 8];
            kb[g][1] = *(const bf16x8*)&Kp[(jw + g * 16 + lr) * Dd + 32 + lg * 8];
        }
        float z0 = 0.f, z1 = 0.f;
        {   // ib = jw: g0 diag-masked; g1 entirely above diagonal (skip)
            bf16x8 qa0 = *(const bf16x8*)&Qp[(jw + lr) * Dd + lg * 8];
            bf16x8 qa1 = *(const bf16x8*)&Qp[(jw + lr) * Dd + 32 + lg * 8];
            f32x4 s = {0.f, 0.f, 0.f, 0.f};
            s = __builtin_amdgcn_mfma_f32_16x16x32_bf16(qa0, kb[0][0], s, 0, 0, 0);
            s = __builtin_amdgcn_mfma_f32_16x16x32_bf16(qa1, kb[0][1], s, 0, 0, 0);
            #pragma unroll
            for (int r = 0; r < 4; ++r) z0 += dmask[r] ? exp2f(s[r]) : 0.f;
        }
        {   // ib = jw+16: g0 unmasked, g1 diag-masked
            bf16x8 qa0 = *(const bf16x8*)&Qp[(jw + 16 + lr) * Dd + lg * 8];
            bf16x8 qa1 = *(const bf16x8*)&Qp[(jw + 16 + lr) * Dd + 32 + lg * 8];
            f32x4 s0 = {0.f, 0.f, 0.f, 0.f}, s1 = {0.f, 0.f, 0.f, 0.f};
            s0 = __builtin_amdgcn_mfma_f32_16x16x32_bf16(qa0, kb[0][0], s0, 0, 0, 0);
            s0 = __builtin_amdgcn_mfma_f32_16x16x32_bf16(qa1, kb[0][1], s0, 0, 0, 0);
            s1 = __builtin_amdgcn_mfma_f32_16x16x32_bf16(qa0, kb[1][0], s1, 0, 0, 0);
            s1 = __builtin_amdgcn_mfma_f32_16x16x32_bf16(qa1, kb[1][1], s1, 0, 0, 0);
            #pragma unroll
            for (int r = 0; r < 4; ++r) {
                z0 += exp2f(s0[r]);
                z1 += dmask[r] ? exp2f(s1[r]) : 0.f;
            }
        }
        for (int ib = jw + 32; ib < Ll; ib += 16) {
            bf16x8 qa0 = *(const bf16x8*)&Qp[(ib + lr) * Dd + lg * 8];
            bf16x8 qa1 = *(const bf16x8*)&Qp[(ib + lr) * Dd + 32 + lg * 8];
            f32x4 s0 = {0.f, 0.f, 0.f, 0.f}, s1 = {0.f, 0.f, 0.f, 0.f};
            s0 = __builtin_amdgcn_mfma_f32_16x16x32_bf16(qa0, kb[0][0], s0, 0, 0, 0);
            s0 = __builtin_amdgcn_mfma_f32_16x16x32_bf16(qa1, kb[0][1], s0, 0, 0, 0);
            s1 = __builtin_amdgcn_mfma_f32_16x16x32_bf16(qa0, kb[1][0], s1, 0, 0, 0);
            s1 = __builtin_amdgcn_mfma_f32_16x16x32_bf16(qa1, kb[1][1], s1, 0, 0, 0);
            #pragma unroll
            for (int r = 0; r < 4; ++r) { z0 += exp2f(s0[r]); z1 += exp2f(s1[r]); }
        }
        z0 += __shfl_xor(z0, 16); z0 += __shfl_xor(z0, 32);
        z1 += __shfl_xor(z1, 16); z1 += __shfl_xor(z1, 32);
        if (lg == 0) {
            zinv[(size_t)bh * Ll + jw + lr]      = 1.f / z0;
            zinv[(size_t)bh * Ll + jw + 16 + lr] = 1.f / z1;
        }
    }
}

// ---------------- attention pass 2: Y = (exp(S') * zinv_j) @ V^T ----------------
// Vt now UNSCALED (written by QKV epilogue); zinv folded into P (f32x4 load per
// cs, shared across both row-halves). Otherwise frozen R4 structure.
__global__ __launch_bounds__(256)
void k_attn_pv(const u16* __restrict__ Q, const u16* __restrict__ Kb,
               const u16* __restrict__ Vt, const float* __restrict__ zinv,
               u16* __restrict__ Y)
{
    __shared__ u16 Plds[4][32 * 72];
    const int tid = threadIdx.x;
    const int wid = tid >> 6, lane = tid & 63;
    const int lr = lane & 15, lg = lane >> 4;
    const int fid = blockIdx.x;
    const int xcd = fid & 7, n = fid >> 3;
    const int pr = n & 3;
    const int bh = (xcd << 4) | (n >> 2);
    const int bidx = bh >> 4, head = bh & 15;
    const u16* Qp = Q  + (size_t)bh * Ll * Dd;
    const u16* Kp = Kb + (size_t)bh * Ll * Dd;
    const u16* Vp = Vt + (size_t)bh * Ll * Dd;     // (Dd, Ll) layout
    const float* zp = zinv + (size_t)bh * Ll;
    u16* pl = &Plds[wid][0];

    #pragma unroll
    for (int t = 0; t < 2; ++t) {
        const int xt = t ? (7 - pr) : pr;
        const int iw = xt * 128 + wid * 32;
        bf16x8 qa[2][2];
        #pragma unroll
        for (int hh = 0; hh < 2; ++hh) {
            qa[hh][0] = *(const bf16x8*)&Qp[(iw + hh * 16 + lr) * Dd + lg * 8];
            qa[hh][1] = *(const bf16x8*)&Qp[(iw + hh * 16 + lr) * Dd + 32 + lg * 8];
        }
        f32x4 yacc[2][4] = {};

        for (int j0 = 0; j0 < iw + 32; j0 += 64) {
            #pragma unroll
            for (int cs = 0; cs < 4; ++cs) {
                int jb = j0 + cs * 16;
                bf16x8 kb0 = *(const bf16x8*)&Kp[(jb + lr) * Dd + lg * 8];
                bf16x8 kb1 = *(const bf16x8*)&Kp[(jb + lr) * Dd + 32 + lg * 8];
                f32x4 zv = *(const f32x4*)&zp[jb + 4 * lg];   // zinv[j], j=jb+4lg+r
                #pragma unroll
                for (int hh = 0; hh < 2; ++hh) {
                    f32x4 s = {0.f, 0.f, 0.f, 0.f};
                    s = __builtin_amdgcn_mfma_f32_16x16x32_bf16(kb0, qa[hh][0], s, 0, 0, 0);
                    s = __builtin_amdgcn_mfma_f32_16x16x32_bf16(kb1, qa[hh][1], s, 0, 0, 0);
                    // lane holds S^T[j = jb+4lg+r][i = iw+hh*16+lr]
                    float p[4];
                    if (jb + 15 <= iw + hh * 16) {
                        #pragma unroll
                        for (int r = 0; r < 4; ++r) p[r] = exp2f(s[r]) * zv[r];
                    } else {
                        int ig = iw + hh * 16 + lr;
                        #pragma unroll
                        for (int r = 0; r < 4; ++r)
                            p[r] = (jb + 4 * lg + r <= ig) ? exp2f(s[r]) * zv[r] : 0.f;
                    }
                    uint2 w;
                    w.x = pack2bf(p[0], p[1]);
                    w.y = pack2bf(p[2], p[3]);
                    *(uint2*)&pl[(hh * 16 + lr) * 72 + cs * 16 + 4 * lg] = w;
                }
            }
            asm volatile("s_waitcnt lgkmcnt(0)" ::: "memory");
            __builtin_amdgcn_sched_barrier(0);
            bf16x8 pa[2][2];
            #pragma unroll
            for (int hh = 0; hh < 2; ++hh) {
                pa[hh][0] = *(const bf16x8*)&pl[(hh * 16 + lr) * 72 + lg * 8];
                pa[hh][1] = *(const bf16x8*)&pl[(hh * 16 + lr) * 72 + 32 + lg * 8];
            }
            #pragma unroll
            for (int ns = 0; ns < 4; ++ns) {
                bf16x8 vb0 = *(const bf16x8*)&Vp[(size_t)(ns * 16 + lr) * Ll + j0 + lg * 8];
                bf16x8 vb1 = *(const bf16x8*)&Vp[(size_t)(ns * 16 + lr) * Ll + j0 + 32 + lg * 8];
                #pragma unroll
                for (int hh = 0; hh < 2; ++hh) {
                    yacc[hh][ns] = __builtin_amdgcn_mfma_f32_16x16x32_bf16(pa[hh][0], vb0, yacc[hh][ns], 0, 0, 0);
                    yacc[hh][ns] = __builtin_amdgcn_mfma_f32_16x16x32_bf16(pa[hh][1], vb1, yacc[hh][ns], 0, 0, 0);
                }
            }
        }
        #pragma unroll
        for (int hh = 0; hh < 2; ++hh)
            #pragma unroll
            for (int ns = 0; ns < 4; ++ns)
                #pragma unroll
                for (int r = 0; r < 4; ++r) {
                    int l2 = iw + hh * 16 + lg * 4 + r;
                    Y[((size_t)bidx * Ll + l2) * Cc + head * Dd + ns * 16 + lr] = f2b(yacc[hh][ns][r]);
                }
    }
}

extern "C" void kernel_launch(void* const* d_in, const int* in_sizes, int n_in,
                              void* d_out, int out_size, void* d_ws, size_t ws_size,
                              hipStream_t stream)
{
    const float* x     = (const float*)d_in[0];
    const float* Wqkv  = (const float*)d_in[1];
    const float* bqkv  = (const float*)d_in[2];
    const float* Wproj = (const float*)d_in[3];
    const float* bproj = (const float*)d_in[4];
    float* out = (float*)d_out;

    char* ws = (char*)d_ws;
    u16* xb     = (u16*)(ws + 0);            // x as bf16, 8192x1024         (16 MB)
    u16* WqkvT  = (u16*)(ws + 16777216);     // W_qkv^T bf16, 3072x1024      (6 MB)
    u16* WprojT = (u16*)(ws + 23068672);     // W_proj^T bf16, 1024x1024     (2 MB)
    u16* q      = (u16*)(ws + 25165824);     // (B,H,L,D) bf16, pre-scaled   (16 MB)
    u16* k      = (u16*)(ws + 41943040);     // (B,H,L,D) bf16               (16 MB)
    u16* yb     = (u16*)(ws + 58720256);     // Y bf16 (B,L,C)               (16 MB)
    u16* vt     = (u16*)(ws + 75497472);     // (B,H,D,L) bf16 (from QKV)    (16 MB)
    float* zinv = (float*)(ws + 92274688);   // (B*H*L) fp32                 (0.5 MB)

    k_f32_to_bf16<<<dim3(2048), dim3(256), 0, stream>>>(x, xb, Mrows * Cc / 16);
    k_transpose_w<<<dim3(128, 32), dim3(32, 8), 0, stream>>>(Wqkv, WqkvT, Wproj, WprojT);
    k_gemm_qkv<<<dim3(N3 / 128, Mrows / 128), dim3(256), 0, stream>>>(
        xb, WqkvT, bqkv, q, k, vt);
    k_attn_colsum<<<dim3(512), dim3(256), 0, stream>>>(q, k, zinv);
    k_attn_pv<<<dim3(512), dim3(256), 0, stream>>>(q, k, vt, zinv, yb);
    k_gemm_proj<<<dim3(Cc / 128, Mrows / 128), dim3(256), 0, stream>>>(
        yb, WprojT, bproj, out);
}

// Round 8
// 238.751 us; speedup vs baseline: 1.0685x; 1.0685x over previous
//
#include <hip/hip_runtime.h>

typedef unsigned short u16;
typedef unsigned int   u32;
using bf16x8 = __attribute__((ext_vector_type(8))) short;
using f32x4  = __attribute__((ext_vector_type(4))) float;
using u32x4  = __attribute__((ext_vector_type(4))) u32;

static constexpr int Bb = 8, Ll = 1024, Cc = 1024, Hh = 16, Dd = 64;
static constexpr int Mrows = Bb * Ll;   // 8192
static constexpr int N3    = 3 * Cc;    // 3072
// exp(S/8) = 2^(S * 0.125*log2(e)); fold into q at the QKV epilogue
static constexpr float QSCALE = 0.125f * 1.44269504088896f;

__device__ __forceinline__ u16 f2b(float f) {  // fp32 -> bf16 RNE
    u32 u = __builtin_bit_cast(u32, f);
    u += 0x7FFFu + ((u >> 16) & 1u);
    return (u16)(u >> 16);
}
__device__ __forceinline__ float b2f(u16 u) {
    return __builtin_bit_cast(float, (u32)u << 16);
}
__device__ __forceinline__ u32 pack2bf(float a, float b) {
    return (u32)f2b(a) | ((u32)f2b(b) << 16);
}
// async global->LDS, 16B/lane; LDS dest is wave-uniform base (lane*16 HW-added)
__device__ __forceinline__ void gload16(const u16* g, u16* l) {
    __builtin_amdgcn_global_load_lds(
        (const __attribute__((address_space(1))) void*)g,
        (__attribute__((address_space(3))) void*)l, 16, 0, 0);
}

// ---------------- fp32 -> bf16 convert, 16 elems/thread ----------------
__global__ void k_f32_to_bf16(const float* __restrict__ in, u16* __restrict__ out, int n16) {
    int idx = blockIdx.x * blockDim.x + threadIdx.x;
    if (idx >= n16) return;
    #pragma unroll
    for (int h = 0; h < 2; ++h) {
        f32x4 v0 = *((const f32x4*)in + idx * 4 + h * 2);
        f32x4 v1 = *((const f32x4*)in + idx * 4 + h * 2 + 1);
        u32x4 o;
        o[0] = pack2bf(v0[0], v0[1]);
        o[1] = pack2bf(v0[2], v0[3]);
        o[2] = pack2bf(v1[0], v1[1]);
        o[3] = pack2bf(v1[2], v1[3]);
        *((u32x4*)out + idx * 2 + h) = o;
    }
}

// ---- fused weight transpose+convert: W_qkv (1024x3072) and W_proj (1024x1024) ----
__global__ void k_transpose_w(const float* __restrict__ Wqkv, u16* __restrict__ WqkvT,
                              const float* __restrict__ Wproj, u16* __restrict__ WprojT) {
    __shared__ float tile[32][33];
    int bx = blockIdx.x;
    const float* in; u16* out; int Cn;
    if (bx < 96) { in = Wqkv;  out = WqkvT;  Cn = N3; }
    else         { in = Wproj; out = WprojT; Cn = Cc; bx -= 96; }
    const int R = Cc;   // 1024 rows for both
    int tx = threadIdx.x, ty = threadIdx.y;
    int c = bx * 32 + tx;
    int rbase = blockIdx.y * 32;
    #pragma unroll
    for (int rr = 0; rr < 4; ++rr)
        tile[ty + rr * 8][tx] = in[(size_t)(rbase + ty + rr * 8) * Cn + c];
    __syncthreads();
    int ro = bx * 32 + ty;
    #pragma unroll
    for (int rr = 0; rr < 4; ++rr)
        out[(size_t)(ro + rr * 8) * R + rbase + tx] = f2b(tile[tx][ty + rr * 8]);
}

// --- batched bf16 transpose: v (bh,L,D) -> vt (bh,D,L)  [proven R2 kernel] ---
__global__ void k_transpose_bf16_batched(const u16* __restrict__ in, u16* __restrict__ out,
                                         int R, int Cn) {
    __shared__ u16 tile[32][33];
    size_t base = (size_t)blockIdx.z * R * Cn;
    int tx = threadIdx.x, ty = threadIdx.y;
    int c = blockIdx.x * 32 + tx;
    int rbase = blockIdx.y * 32;
    #pragma unroll
    for (int rr = 0; rr < 4; ++rr)
        tile[ty + rr * 8][tx] = in[base + (size_t)(rbase + ty + rr * 8) * Cn + c];
    __syncthreads();
    int ro = blockIdx.x * 32 + ty;
    #pragma unroll
    for (int rr = 0; rr < 4; ++rr)
        out[base + (size_t)(ro + rr * 8) * R + rbase + tx] = tile[tx][ty + rr * 8];
}

// ---------------- 128x128 bf16 MFMA GEMM for QKV (reg-staged, stride-40 LDS) ----------------
// EXACT R6 structure AND epilogue (proven 84.4 us). q,k,v all written to
// (B,H,L,D) with coalesced 32B runs. DO NOT PERTURB (burned 3x: R4 m97 port,
// R5 AF32 fuse, R7 transposed-v epilogue all regressed).
__global__ __launch_bounds__(256)
void k_gemm_qkv(const u16* __restrict__ A, const u16* __restrict__ Bt,
                const float* __restrict__ bias,
                u16* __restrict__ qo, u16* __restrict__ ko, u16* __restrict__ vo)
{
    const int K = Cc;
    __shared__ u16 As[128 * 40];
    __shared__ u16 Bs[128 * 40];
    const int tid = threadIdx.x;
    const int wid = tid >> 6, lane = tid & 63;
    const int lr = lane & 15, lg = lane >> 4;
    const int wr = wid >> 1, wc = wid & 1;
    const int nwg = gridDim.x * gridDim.y;
    const int flat = blockIdx.y * gridDim.x + blockIdx.x;
    const int swz = (flat & 7) * (nwg >> 3) + (flat >> 3);
    const int bx = swz % gridDim.x, by = swz / gridDim.x;
    const int row0 = by * 128, col0 = bx * 128;

    const int sRow = tid >> 2;          // 0..63
    const int sK   = (tid & 3) << 3;    // 0,8,16,24
    const u16* aP = A  + (size_t)(row0 + sRow) * K + sK;
    const u16* bP = Bt + (size_t)(col0 + sRow) * K + sK;
    const size_t half = (size_t)64 * K;

    f32x4 acc[4][4] = {};

    u32x4 ra0 = *(const u32x4*)aP;
    u32x4 ra1 = *(const u32x4*)(aP + half);
    u32x4 rb0 = *(const u32x4*)bP;
    u32x4 rb1 = *(const u32x4*)(bP + half);

    for (int k0 = 0; k0 < K; k0 += 32) {
        __syncthreads();
        *(u32x4*)&As[sRow * 40 + sK]        = ra0;
        *(u32x4*)&As[(64 + sRow) * 40 + sK] = ra1;
        *(u32x4*)&Bs[sRow * 40 + sK]        = rb0;
        *(u32x4*)&Bs[(64 + sRow) * 40 + sK] = rb1;
        __syncthreads();
        if (k0 + 32 < K) {               // prefetch next K-tile (overlaps MFMA)
            ra0 = *(const u32x4*)(aP + k0 + 32);
            ra1 = *(const u32x4*)(aP + half + k0 + 32);
            rb0 = *(const u32x4*)(bP + k0 + 32);
            rb1 = *(const u32x4*)(bP + half + k0 + 32);
        }
        bf16x8 af[4], bfv[4];
        #pragma unroll
        for (int m = 0; m < 4; ++m)
            af[m] = *(const bf16x8*)&As[(wr * 64 + m * 16 + lr) * 40 + lg * 8];
        #pragma unroll
        for (int n = 0; n < 4; ++n)
            bfv[n] = *(const bf16x8*)&Bs[(wc * 64 + n * 16 + lr) * 40 + lg * 8];
        #pragma unroll
        for (int m = 0; m < 4; ++m)
            #pragma unroll
            for (int n = 0; n < 4; ++n)
                acc[m][n] = __builtin_amdgcn_mfma_f32_16x16x32_bf16(af[m], bfv[n], acc[m][n], 0, 0, 0);
    }

    #pragma unroll
    for (int m = 0; m < 4; ++m) {
        int rb2 = row0 + wr * 64 + m * 16 + lg * 4;
        #pragma unroll
        for (int n = 0; n < 4; ++n) {
            int cg = col0 + wc * 64 + n * 16 + lr;
            float bv = bias[cg];
            int which = cg >> 10;         // 0=q 1=k 2=v
            float sc = (which == 0) ? QSCALE : 1.0f;   // fold attn scale into q
            int cc2 = cg & 1023;
            int h = cc2 >> 6, dd = cc2 & 63;
            #pragma unroll
            for (int r = 0; r < 4; ++r) {
                int rg = rb2 + r;
                int bidx = rg >> 10, ll2 = rg & 1023;
                size_t o = ((size_t)(bidx * Hh + h) * Ll + ll2) * Dd + dd;
                u16 val = f2b((acc[m][n][r] + bv) * sc);
                if (which == 0) qo[o] = val;
                else if (which == 1) ko[o] = val;
                else vo[o] = val;
            }
        }
    }
}

// ---- proj GEMM: 2-phase dbuf + global_load_lds + source-side XOR swizzle ----
// Kept from R7 (rest-of-pipeline improved ~11us with this in).
__global__ __launch_bounds__(256)
void k_gemm_proj(const u16* __restrict__ A, const u16* __restrict__ Bt,
                 const float* __restrict__ bias, float* __restrict__ outf)
{
    const int N = Cc, K = Cc;
    __shared__ u16 As[2][128 * 32];
    __shared__ u16 Bs[2][128 * 32];
    const int tid = threadIdx.x;
    const int wid = tid >> 6, lane = tid & 63;
    const int lr = lane & 15, lg = lane >> 4;
    const int wr = wid >> 1, wc = wid & 1;
    const int nwg = gridDim.x * gridDim.y;
    const int flat = blockIdx.y * gridDim.x + blockIdx.x;
    const int swz = (flat & 7) * (nwg >> 3) + (flat >> 3);
    const int bx = swz % gridDim.x, by = swz / gridDim.x;
    const int row0 = by * 128, col0 = bx * 128;

    const int srow = wid * 32 + (lane >> 2);
    const int schk = (lane & 3) ^ (srow & 3);
    const u16* aP = A  + (size_t)(row0 + srow) * K + schk * 8;
    const u16* bP = Bt + (size_t)(col0 + srow) * K + schk * 8;
    const size_t r16 = (size_t)16 * K;
    u16* aL0 = &As[0][wid * 32 * 32]; u16* aL0b = aL0 + 16 * 32;
    u16* bL0 = &Bs[0][wid * 32 * 32]; u16* bL0b = bL0 + 16 * 32;
    u16* aL1 = &As[1][wid * 32 * 32]; u16* aL1b = aL1 + 16 * 32;
    u16* bL1 = &Bs[1][wid * 32 * 32]; u16* bL1b = bL1 + 16 * 32;

    f32x4 acc[4][4] = {};

#define STAGE0(kk) { gload16(aP + (kk), aL0); gload16(aP + r16 + (kk), aL0b); \
                     gload16(bP + (kk), bL0); gload16(bP + r16 + (kk), bL0b); }
#define STAGE1(kk) { gload16(aP + (kk), aL1); gload16(aP + r16 + (kk), aL1b); \
                     gload16(bP + (kk), bL1); gload16(bP + r16 + (kk), bL1b); }
#define COMPUTE(bufi) { \
        bf16x8 af[4], bfv[4]; \
        _Pragma("unroll") \
        for (int m = 0; m < 4; ++m) { int rw = wr * 64 + m * 16 + lr; \
            af[m] = *(const bf16x8*)&As[bufi][rw * 32 + ((lg ^ (rw & 3)) * 8)]; } \
        _Pragma("unroll") \
        for (int n = 0; n < 4; ++n) { int rw = wc * 64 + n * 16 + lr; \
            bfv[n] = *(const bf16x8*)&Bs[bufi][rw * 32 + ((lg ^ (rw & 3)) * 8)]; } \
        _Pragma("unroll") \
        for (int m = 0; m < 4; ++m) \
            _Pragma("unroll") \
            for (int n = 0; n < 4; ++n) \
                acc[m][n] = __builtin_amdgcn_mfma_f32_16x16x32_bf16(af[m], bfv[n], acc[m][n], 0, 0, 0); }

    STAGE0(0);
    __syncthreads();
    for (int k0 = 0; k0 < K; k0 += 64) {
        if (k0 + 32 < K) STAGE1(k0 + 32);
        COMPUTE(0);
        __syncthreads();
        if (k0 + 64 < K) STAGE0(k0 + 64);
        COMPUTE(1);
        __syncthreads();
    }
#undef STAGE0
#undef STAGE1
#undef COMPUTE

    #pragma unroll
    for (int m = 0; m < 4; ++m) {
        int rb2 = row0 + wr * 64 + m * 16 + lg * 4;
        #pragma unroll
        for (int n = 0; n < 4; ++n) {
            int cg = col0 + wc * 64 + n * 16 + lr;
            float bv = bias[cg];
            #pragma unroll
            for (int r = 0; r < 4; ++r)
                outf[(size_t)(rb2 + r) * N + cg] = acc[m][n][r] + bv;
        }
    }
}

// ---------------- attention pass 1: column sums ----------------
__global__ __launch_bounds__(256)
void k_attn_colsum(const u16* __restrict__ Q, const u16* __restrict__ Kb,
                   float* __restrict__ zinv)
{
    const int tid = threadIdx.x;
    const int wid = tid >> 6, lane = tid & 63;
    const int lr = lane & 15, lg = lane >> 4;
    const int fid = blockIdx.x;
    const int xcd = fid & 7, n = fid >> 3;
    const int pr = n & 3;
    const int bh = (xcd << 4) | (n >> 2);
    const u16* Qp = Q  + (size_t)bh * Ll * Dd;
    const u16* Kp = Kb + (size_t)bh * Ll * Dd;
    const bool dmask[4] = { lg * 4 + 0 >= lr, lg * 4 + 1 >= lr,
                            lg * 4 + 2 >= lr, lg * 4 + 3 >= lr };

    #pragma unroll
    for (int t = 0; t < 2; ++t) {
        const int xt = t ? (7 - pr) : pr;
        const int jw = xt * 128 + wid * 32;
        bf16x8 kb[2][2];
        #pragma unroll
        for (int g = 0; g < 2; ++g) {
            kb[g][0] = *(const bf16x8*)&Kp[(jw + g * 16 + lr) * Dd + lg * 8];
            kb[g][1] = *(const bf16x8*)&Kp[(jw + g * 16 + lr) * Dd + 32 + lg * 8];
        }
        float z0 = 0.f, z1 = 0.f;
        {   // ib = jw: g0 diag-masked; g1 entirely above diagonal (skip)
            bf16x8 qa0 = *(const bf16x8*)&Qp[(jw + lr) * Dd + lg * 8];
            bf16x8 qa1 = *(const bf16x8*)&Qp[(jw + lr) * Dd + 32 + lg * 8];
            f32x4 s = {0.f, 0.f, 0.f, 0.f};
            s = __builtin_amdgcn_mfma_f32_16x16x32_bf16(qa0, kb[0][0], s, 0, 0, 0);
            s = __builtin_amdgcn_mfma_f32_16x16x32_bf16(qa1, kb[0][1], s, 0, 0, 0);
            #pragma unroll
            for (int r = 0; r < 4; ++r) z0 += dmask[r] ? exp2f(s[r]) : 0.f;
        }
        {   // ib = jw+16: g0 unmasked, g1 diag-masked
            bf16x8 qa0 = *(const bf16x8*)&Qp[(jw + 16 + lr) * Dd + lg * 8];
            bf16x8 qa1 = *(const bf16x8*)&Qp[(jw + 16 + lr) * Dd + 32 + lg * 8];
            f32x4 s0 = {0.f, 0.f, 0.f, 0.f}, s1 = {0.f, 0.f, 0.f, 0.f};
            s0 = __builtin_amdgcn_mfma_f32_16x16x32_bf16(qa0, kb[0][0], s0, 0, 0, 0);
            s0 = __builtin_amdgcn_mfma_f32_16x16x32_bf16(qa1, kb[0][1], s0, 0, 0, 0);
            s1 = __builtin_amdgcn_mfma_f32_16x16x32_bf16(qa0, kb[1][0], s1, 0, 0, 0);
            s1 = __builtin_amdgcn_mfma_f32_16x16x32_bf16(qa1, kb[1][1], s1, 0, 0, 0);
            #pragma unroll
            for (int r = 0; r < 4; ++r) {
                z0 += exp2f(s0[r]);
                z1 += dmask[r] ? exp2f(s1[r]) : 0.f;
            }
        }
        for (int ib = jw + 32; ib < Ll; ib += 16) {
            bf16x8 qa0 = *(const bf16x8*)&Qp[(ib + lr) * Dd + lg * 8];
            bf16x8 qa1 = *(const bf16x8*)&Qp[(ib + lr) * Dd + 32 + lg * 8];
            f32x4 s0 = {0.f, 0.f, 0.f, 0.f}, s1 = {0.f, 0.f, 0.f, 0.f};
            s0 = __builtin_amdgcn_mfma_f32_16x16x32_bf16(qa0, kb[0][0], s0, 0, 0, 0);
            s0 = __builtin_amdgcn_mfma_f32_16x16x32_bf16(qa1, kb[0][1], s0, 0, 0, 0);
            s1 = __builtin_amdgcn_mfma_f32_16x16x32_bf16(qa0, kb[1][0], s1, 0, 0, 0);
            s1 = __builtin_amdgcn_mfma_f32_16x16x32_bf16(qa1, kb[1][1], s1, 0, 0, 0);
            #pragma unroll
            for (int r = 0; r < 4; ++r) { z0 += exp2f(s0[r]); z1 += exp2f(s1[r]); }
        }
        z0 += __shfl_xor(z0, 16); z0 += __shfl_xor(z0, 32);
        z1 += __shfl_xor(z1, 16); z1 += __shfl_xor(z1, 32);
        if (lg == 0) {
            zinv[(size_t)bh * Ll + jw + lr]      = 1.f / z0;
            zinv[(size_t)bh * Ll + jw + 16 + lr] = 1.f / z1;
        }
    }
}

// ---------------- attention pass 2: Y = (exp(S') * zinv_j) @ V^T ----------------
__global__ __launch_bounds__(256)
void k_attn_pv(const u16* __restrict__ Q, const u16* __restrict__ Kb,
               const u16* __restrict__ Vt, const float* __restrict__ zinv,
               u16* __restrict__ Y)
{
    __shared__ u16 Plds[4][32 * 72];
    const int tid = threadIdx.x;
    const int wid = tid >> 6, lane = tid & 63;
    const int lr = lane & 15, lg = lane >> 4;
    const int fid = blockIdx.x;
    const int xcd = fid & 7, n = fid >> 3;
    const int pr = n & 3;
    const int bh = (xcd << 4) | (n >> 2);
    const int bidx = bh >> 4, head = bh & 15;
    const u16* Qp = Q  + (size_t)bh * Ll * Dd;
    const u16* Kp = Kb + (size_t)bh * Ll * Dd;
    const u16* Vp = Vt + (size_t)bh * Ll * Dd;     // (Dd, Ll) layout
    const float* zp = zinv + (size_t)bh * Ll;
    u16* pl = &Plds[wid][0];

    #pragma unroll
    for (int t = 0; t < 2; ++t) {
        const int xt = t ? (7 - pr) : pr;
        const int iw = xt * 128 + wid * 32;
        bf16x8 qa[2][2];
        #pragma unroll
        for (int hh = 0; hh < 2; ++hh) {
            qa[hh][0] = *(const bf16x8*)&Qp[(iw + hh * 16 + lr) * Dd + lg * 8];
            qa[hh][1] = *(const bf16x8*)&Qp[(iw + hh * 16 + lr) * Dd + 32 + lg * 8];
        }
        f32x4 yacc[2][4] = {};

        for (int j0 = 0; j0 < iw + 32; j0 += 64) {
            #pragma unroll
            for (int cs = 0; cs < 4; ++cs) {
                int jb = j0 + cs * 16;
                bf16x8 kb0 = *(const bf16x8*)&Kp[(jb + lr) * Dd + lg * 8];
                bf16x8 kb1 = *(const bf16x8*)&Kp[(jb + lr) * Dd + 32 + lg * 8];
                f32x4 zv = *(const f32x4*)&zp[jb + 4 * lg];   // zinv[j], j=jb+4lg+r
                #pragma unroll
                for (int hh = 0; hh < 2; ++hh) {
                    f32x4 s = {0.f, 0.f, 0.f, 0.f};
                    s = __builtin_amdgcn_mfma_f32_16x16x32_bf16(kb0, qa[hh][0], s, 0, 0, 0);
                    s = __builtin_amdgcn_mfma_f32_16x16x32_bf16(kb1, qa[hh][1], s, 0, 0, 0);
                    float p[4];
                    if (jb + 15 <= iw + hh * 16) {
                        #pragma unroll
                        for (int r = 0; r < 4; ++r) p[r] = exp2f(s[r]) * zv[r];
                    } else {
                        int ig = iw + hh * 16 + lr;
                        #pragma unroll
                        for (int r = 0; r < 4; ++r)
                            p[r] = (jb + 4 * lg + r <= ig) ? exp2f(s[r]) * zv[r] : 0.f;
                    }
                    uint2 w;
                    w.x = pack2bf(p[0], p[1]);
                    w.y = pack2bf(p[2], p[3]);
                    *(uint2*)&pl[(hh * 16 + lr) * 72 + cs * 16 + 4 * lg] = w;
                }
            }
            asm volatile("s_waitcnt lgkmcnt(0)" ::: "memory");
            __builtin_amdgcn_sched_barrier(0);
            bf16x8 pa[2][2];
            #pragma unroll
            for (int hh = 0; hh < 2; ++hh) {
                pa[hh][0] = *(const bf16x8*)&pl[(hh * 16 + lr) * 72 + lg * 8];
                pa[hh][1] = *(const bf16x8*)&pl[(hh * 16 + lr) * 72 + 32 + lg * 8];
            }
            #pragma unroll
            for (int ns = 0; ns < 4; ++ns) {
                bf16x8 vb0 = *(const bf16x8*)&Vp[(size_t)(ns * 16 + lr) * Ll + j0 + lg * 8];
                bf16x8 vb1 = *(const bf16x8*)&Vp[(size_t)(ns * 16 + lr) * Ll + j0 + 32 + lg * 8];
                #pragma unroll
                for (int hh = 0; hh < 2; ++hh) {
                    yacc[hh][ns] = __builtin_amdgcn_mfma_f32_16x16x32_bf16(pa[hh][0], vb0, yacc[hh][ns], 0, 0, 0);
                    yacc[hh][ns] = __builtin_amdgcn_mfma_f32_16x16x32_bf16(pa[hh][1], vb1, yacc[hh][ns], 0, 0, 0);
                }
            }
        }
        #pragma unroll
        for (int hh = 0; hh < 2; ++hh)
            #pragma unroll
            for (int ns = 0; ns < 4; ++ns)
                #pragma unroll
                for (int r = 0; r < 4; ++r) {
                    int l2 = iw + hh * 16 + lg * 4 + r;
                    Y[((size_t)bidx * Ll + l2) * Cc + head * Dd + ns * 16 + lr] = f2b(yacc[hh][ns][r]);
                }
    }
}

extern "C" void kernel_launch(void* const* d_in, const int* in_sizes, int n_in,
                              void* d_out, int out_size, void* d_ws, size_t ws_size,
                              hipStream_t stream)
{
    const float* x     = (const float*)d_in[0];
    const float* Wqkv  = (const float*)d_in[1];
    const float* bqkv  = (const float*)d_in[2];
    const float* Wproj = (const float*)d_in[3];
    const float* bproj = (const float*)d_in[4];
    float* out = (float*)d_out;

    char* ws = (char*)d_ws;
    u16* xb     = (u16*)(ws + 0);            // x as bf16, 8192x1024         (16 MB)
    u16* WqkvT  = (u16*)(ws + 16777216);     // W_qkv^T bf16, 3072x1024      (6 MB)
    u16* WprojT = (u16*)(ws + 23068672);     // W_proj^T bf16, 1024x1024     (2 MB)
    u16* q      = (u16*)(ws + 25165824);     // (B,H,L,D) bf16, pre-scaled   (16 MB)
    u16* k      = (u16*)(ws + 41943040);     // (B,H,L,D) bf16               (16 MB)
    u16* v      = (u16*)(ws + 58720256);     // (B,H,L,D) bf16; reused as Y  (16 MB)
    u16* vt     = (u16*)(ws + 75497472);     // (B,H,D,L) bf16               (16 MB)
    float* zinv = (float*)(ws + 92274688);   // (B*H*L) fp32                 (0.5 MB)

    k_f32_to_bf16<<<dim3(2048), dim3(256), 0, stream>>>(x, xb, Mrows * Cc / 16);
    k_transpose_w<<<dim3(128, 32), dim3(32, 8), 0, stream>>>(Wqkv, WqkvT, Wproj, WprojT);
    k_gemm_qkv<<<dim3(N3 / 128, Mrows / 128), dim3(256), 0, stream>>>(
        xb, WqkvT, bqkv, q, k, v);
    k_attn_colsum<<<dim3(512), dim3(256), 0, stream>>>(q, k, zinv);
    k_transpose_bf16_batched<<<dim3(2, 32, Bb * Hh), dim3(32, 8), 0, stream>>>(v, vt, Ll, Dd);
    k_attn_pv<<<dim3(512), dim3(256), 0, stream>>>(q, k, vt, zinv, v);
    k_gemm_proj<<<dim3(Cc / 128, Mrows / 128), dim3(256), 0, stream>>>(
        v, WprojT, bproj, out);
}